// Round 1
// baseline (1272.358 us; speedup 1.0000x reference)
//
#include <hip/hip_runtime.h>
#include <math.h>

// ---- Problem constants (fixed by the reference) ----
constexpr int BATCH = 262144;
constexpr int M_  = 2;
constexpr int N_  = 4;
constexpr int NB_ = 5;
constexpr int NH_ = 8;
constexpr int HD_ = 4;
constexpr int HID_ = 32;
constexpr float D_v    = 50.0f;
constexpr float HZ_v   = 5.0f;
constexpr float DMIN_v = 0.025f;
constexpr float PMAX_v = 1.0f;
constexpr float SCALE_v = 0.5f;                      // 1/sqrt(HD)
constexpr float BMAX_v  = 2.0f * D_v - (N_ - 1) * DMIN_v;  // 99.925

__device__ __forceinline__ float frcp(float x) { return __builtin_amdgcn_rcpf(x); }

// One thread = one batch element. All weight reads are wave-uniform -> SGPRs.
// LayerNorm is algebraically deferred so acat/ucat (192 floats) are never
// materialized; instead we accumulate S[j]=sum_i x_i*g_i*w1[j,i], sum_x,
// sum_x^2 per row, head by head. Weight-only sums G[j]=sum_i g_i*w1[j,i] and
// B'[j]=sum_i b_i*w1[j,i]+b1[j] are precomputed once per block into LDS.
__global__ __launch_bounds__(256) void bgat_fwd(
    const float* __restrict__ users, const float* __restrict__ delta_init,
    const float* __restrict__ power_init,
    const float* __restrict__ Wu, const float* __restrict__ Wa,
    const float* __restrict__ We, const float* __restrict__ av,
    const float* __restrict__ Wres,
    const float* __restrict__ lnu_g, const float* __restrict__ lnu_b,
    const float* __restrict__ lna_g, const float* __restrict__ lna_b,
    const float* __restrict__ mu_w1, const float* __restrict__ mu_b1,
    const float* __restrict__ mu_w2, const float* __restrict__ mu_b2,
    const float* __restrict__ ma_w1, const float* __restrict__ ma_b1,
    const float* __restrict__ ma_w2, const float* __restrict__ ma_b2,
    const float* __restrict__ rd_w1, const float* __restrict__ rd_b1,
    const float* __restrict__ rd_w2, const float* __restrict__ rd_b2,
    const float* __restrict__ rp_w1, const float* __restrict__ rp_b1,
    const float* __restrict__ rp_w2, const float* __restrict__ rp_b2,
    float* __restrict__ out)
{
    __shared__ float sG[NB_][2][16];   // [layer][0=mu,1=ma][j]
    __shared__ float sB[NB_][2][16];
    {
        const int idx = threadIdx.x;
        if (idx < NB_ * 2 * 16) {
            const int d = idx >> 5, rem = idx & 31, br = rem >> 4, j = rem & 15;
            const float* w1 = (br == 0 ? mu_w1 : ma_w1) + (d * 16 + j) * HID_;
            const float* g  = (br == 0 ? lnu_g : lna_g) + d * HID_;
            const float* bb = (br == 0 ? lnu_b : lna_b) + d * HID_;
            const float* b1 = (br == 0 ? mu_b1 : ma_b1) + d * 16;
            float G = 0.f, Bp = 0.f;
            for (int i = 0; i < HID_; ++i) { G = fmaf(g[i], w1[i], G); Bp = fmaf(bb[i], w1[i], Bp); }
            sG[d][br][j] = G;
            sB[d][br][j] = Bp + b1[j];
        }
    }
    __syncthreads();

    const int b = blockIdx.x * blockDim.x + threadIdx.x;

    float uf[M_][2];
    {
        const float4 u = ((const float4*)users)[b];
        uf[0][0] = u.x; uf[0][1] = u.y; uf[1][0] = u.z; uf[1][1] = u.w;
    }
    float af[N_][2];
    {
        const float4 p  = ((const float4*)power_init)[b];
        const float4 dl = ((const float4*)delta_init)[b];
        af[0][0] = p.x;  af[1][0] = p.y;  af[2][0] = p.z;  af[3][0] = p.w;
        af[0][1] = dl.x; af[1][1] = dl.y; af[2][1] = dl.z; af[3][1] = dl.w;
    }

#pragma unroll 1
    for (int d = 0; d < NB_; ++d) {
        // ---- node positions & edges ----
        float da[N_], sd = 1e-6f;
#pragma unroll
        for (int n = 0; n < N_; ++n) { da[n] = fmaxf(af[n][1], 0.f); sd += da[n]; }
        const float rs = BMAX_v * frcp(sd);
        float xpos[N_];
        {
            float cum = 0.f;
#pragma unroll
            for (int n = 0; n < N_; ++n) {
                cum = fmaf(rs, da[n], cum);
                xpos[n] = cum - D_v + DMIN_v * (float)n;
            }
        }
        float edge[M_][N_];
#pragma unroll
        for (int m = 0; m < M_; ++m)
#pragma unroll
            for (int n = 0; n < N_; ++n) {
                const float dx = uf[m][0] - xpos[n], dy = uf[m][1];
                edge[m][n] = sqrtf(fmaf(dx, dx, dy * dy));
            }

        // ---- deferred-LN accumulators ----
        float Smu[M_][16], Sma[N_][16];
        float sxu[M_], sxxu[M_], sxa[N_], sxxa[N_];
#pragma unroll
        for (int m = 0; m < M_; ++m) {
            sxu[m] = 0.f; sxxu[m] = 0.f;
#pragma unroll
            for (int j = 0; j < 16; ++j) Smu[m][j] = 0.f;
        }
#pragma unroll
        for (int n = 0; n < N_; ++n) {
            sxa[n] = 0.f; sxxa[n] = 0.f;
#pragma unroll
            for (int j = 0; j < 16; ++j) Sma[n][j] = 0.f;
        }

        // ---- attention heads ----
#pragma unroll
        for (int k = 0; k < NH_; ++k) {
            const float* wu  = Wu + (d * NH_ + k) * HD_ * 2;
            const float* wa  = Wa + (d * NH_ + k) * HD_ * 2;
            const float* we  = We + (d * NH_ + k) * HD_;
            const float* avk = av + (d * NH_ + k) * HD_;

            float U[M_][HD_], A[N_][HD_];
#pragma unroll
            for (int h = 0; h < HD_; ++h) {
                const float w0 = wu[h * 2], w1v = wu[h * 2 + 1];
#pragma unroll
                for (int m = 0; m < M_; ++m) U[m][h] = fmaf(uf[m][0], w0, uf[m][1] * w1v);
                const float a0 = wa[h * 2], a1 = wa[h * 2 + 1];
#pragma unroll
                for (int n = 0; n < N_; ++n) A[n][h] = fmaf(af[n][0], a0, af[n][1] * a1);
            }

            float alpha[M_][N_];
#pragma unroll
            for (int m = 0; m < M_; ++m) {
                float sc[N_];
#pragma unroll
                for (int n = 0; n < N_; ++n) {
                    const float e = edge[m][n];
                    float s = 0.f;
#pragma unroll
                    for (int h = 0; h < HD_; ++h) {
                        float t = U[m][h] + A[n][h] + e * we[h];
                        t = fmaxf(t, 0.2f * t);            // leaky_relu(0.2)
                        s = fmaf(t, avk[h], s);
                    }
                    sc[n] = s * SCALE_v;
                }
                const float mx = fmaxf(fmaxf(sc[0], sc[1]), fmaxf(sc[2], sc[3]));
                float den = 0.f;
#pragma unroll
                for (int n = 0; n < N_; ++n) { sc[n] = __expf(sc[n] - mx); den += sc[n]; }
                const float rden = frcp(den);
#pragma unroll
                for (int n = 0; n < N_; ++n) alpha[m][n] = sc[n] * rden;
            }

            // ---- user aggregation: uo[m,h] = sum_n A*alpha + We[h]*sum_n edge*alpha
#pragma unroll
            for (int m = 0; m < M_; ++m) {
                float ea = 0.f;
#pragma unroll
                for (int n = 0; n < N_; ++n) ea = fmaf(edge[m][n], alpha[m][n], ea);
#pragma unroll
                for (int h = 0; h < HD_; ++h) {
                    float uo = ea * we[h];
#pragma unroll
                    for (int n = 0; n < N_; ++n) uo = fmaf(A[n][h], alpha[m][n], uo);
                    const int col = k * HD_ + h;
                    const float r0 = Wres[(d * HID_ + col) * 2];
                    const float r1 = Wres[(d * HID_ + col) * 2 + 1];
                    const float x = uo + fmaf(uf[m][0], r0, uf[m][1] * r1);
                    sxu[m] += x;
                    sxxu[m] = fmaf(x, x, sxxu[m]);
                    const float y = x * lnu_g[d * HID_ + col];
                    const float* w1c = mu_w1 + d * 16 * HID_ + col;
#pragma unroll
                    for (int j = 0; j < 16; ++j) Smu[m][j] = fmaf(y, w1c[j * HID_], Smu[m][j]);
                }
            }

            // ---- node aggregation: ao[n,h] = sum_m U*alpha + We[h]*sum_m edge*alpha
#pragma unroll
            for (int n = 0; n < N_; ++n) {
                const float ea = fmaf(edge[0][n], alpha[0][n], edge[1][n] * alpha[1][n]);
#pragma unroll
                for (int h = 0; h < HD_; ++h) {
                    const float x = fmaf(U[0][h], alpha[0][n],
                                    fmaf(U[1][h], alpha[1][n], ea * we[h]));
                    const int col = k * HD_ + h;
                    sxa[n] += x;
                    sxxa[n] = fmaf(x, x, sxxa[n]);
                    const float y = x * lna_g[d * HID_ + col];
                    const float* w1c = ma_w1 + d * 16 * HID_ + col;
#pragma unroll
                    for (int j = 0; j < 16; ++j) Sma[n][j] = fmaf(y, w1c[j * HID_], Sma[n][j]);
                }
            }
        } // heads

        // ---- user MLP (LN folded) ----
        float nuf[M_][2];
#pragma unroll
        for (int m = 0; m < M_; ++m) {
            const float mu_ = sxu[m] * (1.0f / HID_);
            const float var = sxxu[m] * (1.0f / HID_) - mu_ * mu_;
            const float inv = rsqrtf(var + 1e-5f);
            float o0 = mu_b2[d * 2], o1 = mu_b2[d * 2 + 1];
#pragma unroll
            for (int j = 0; j < 16; ++j) {
                const float pre = fmaf(inv, Smu[m][j] - mu_ * sG[d][0][j], sB[d][0][j]);
                const float hh = fmaxf(pre, 0.f);
                o0 = fmaf(hh, mu_w2[(d * 2 + 0) * 16 + j], o0);
                o1 = fmaf(hh, mu_w2[(d * 2 + 1) * 16 + j], o1);
            }
            nuf[m][0] = o0; nuf[m][1] = o1;
        }
        // ---- node MLP (LN folded) ----
        float naf[N_][2];
#pragma unroll
        for (int n = 0; n < N_; ++n) {
            const float mu_ = sxa[n] * (1.0f / HID_);
            const float var = sxxa[n] * (1.0f / HID_) - mu_ * mu_;
            const float inv = rsqrtf(var + 1e-5f);
            float o0 = ma_b2[d * 2], o1 = ma_b2[d * 2 + 1];
#pragma unroll
            for (int j = 0; j < 16; ++j) {
                const float pre = fmaf(inv, Sma[n][j] - mu_ * sG[d][1][j], sB[d][1][j]);
                const float hh = fmaxf(pre, 0.f);
                o0 = fmaf(hh, ma_w2[(d * 2 + 0) * 16 + j], o0);
                o1 = fmaf(hh, ma_w2[(d * 2 + 1) * 16 + j], o1);
            }
            naf[n][0] = o0; naf[n][1] = o1;
        }
#pragma unroll
        for (int m = 0; m < M_; ++m) { uf[m][0] = nuf[m][0]; uf[m][1] = nuf[m][1]; }
#pragma unroll
        for (int n = 0; n < N_; ++n) { af[n][0] = naf[n][0]; af[n][1] = naf[n][1]; }
    } // layers

    // ---- delta readout ----
    float hid[8];
#pragma unroll
    for (int j = 0; j < 8; ++j) {
        float s = rd_b1[j];
#pragma unroll
        for (int n = 0; n < N_; ++n) s = fmaf(af[n][1], rd_w1[j * N_ + n], s);
        hid[j] = fmaxf(s, 0.f);
    }
    float daux[N_];
    float sumd = 0.f;
#pragma unroll
    for (int n = 0; n < N_; ++n) {
        float s = rd_b2[n];
#pragma unroll
        for (int j = 0; j < 8; ++j) s = fmaf(hid[j], rd_w2[n * 8 + j], s);
        daux[n] = fmaxf(s, 0.001f);
        sumd += daux[n];
    }
    const float sdl = BMAX_v * frcp(sumd);
    float sdelta[N_], xf[N_];
    {
        float cum = 0.f;
#pragma unroll
        for (int n = 0; n < N_; ++n) {
            sdelta[n] = sdl * daux[n];
            cum += sdelta[n];
            xf[n] = cum + DMIN_v * (float)n - D_v * (float)(n + 1);
        }
    }

    // ---- power readout ----
    float hp[8];
#pragma unroll
    for (int j = 0; j < 8; ++j) {
        float s = rp_b1[j];
#pragma unroll
        for (int n = 0; n < N_; ++n) s = fmaf(af[n][0], rp_w1[j * N_ + n], s);
        hp[j] = fmaxf(s, 0.f);
    }
    float paux[N_];
    float sump = 1e-6f;
#pragma unroll
    for (int n = 0; n < N_; ++n) {
        float s = rp_b2[n];
#pragma unroll
        for (int j = 0; j < 8; ++j) s = fmaf(hp[j], rp_w2[n * 8 + j], s);
        paux[n] = fmaxf(s, 0.001f);
        sump += paux[n];
    }
    const float pscale = PMAX_v * frcp(fmaxf(PMAX_v, sump));

    // ---- stores: scaled_power (B,4) | scaled_delta (B,4) | final_positions (B,4,3)
    float4 sp;
    sp.x = pscale * paux[0]; sp.y = pscale * paux[1];
    sp.z = pscale * paux[2]; sp.w = pscale * paux[3];
    ((float4*)out)[b] = sp;

    float4 sdv;
    sdv.x = sdelta[0]; sdv.y = sdelta[1]; sdv.z = sdelta[2]; sdv.w = sdelta[3];
    ((float4*)(out + (size_t)4 * BATCH))[b] = sdv;

    float* pos = out + (size_t)8 * BATCH + (size_t)b * 12;
    float4 p0, p1, p2;
    p0.x = xf[0]; p0.y = 0.f;   p0.z = HZ_v;  p0.w = xf[1];
    p1.x = 0.f;   p1.y = HZ_v;  p1.z = xf[2]; p1.w = 0.f;
    p2.x = HZ_v;  p2.y = xf[3]; p2.z = 0.f;   p2.w = HZ_v;
    ((float4*)pos)[0] = p0;
    ((float4*)pos)[1] = p1;
    ((float4*)pos)[2] = p2;
}

extern "C" void kernel_launch(void* const* d_in, const int* in_sizes, int n_in,
                              void* d_out, int out_size, void* d_ws, size_t ws_size,
                              hipStream_t stream) {
    const float* users      = (const float*)d_in[0];
    const float* delta_init = (const float*)d_in[1];
    const float* power_init = (const float*)d_in[2];
    const float* Wu    = (const float*)d_in[3];
    const float* Wa    = (const float*)d_in[4];
    const float* We    = (const float*)d_in[5];
    const float* av    = (const float*)d_in[6];
    const float* Wres  = (const float*)d_in[7];
    const float* lnu_g = (const float*)d_in[8];
    const float* lnu_b = (const float*)d_in[9];
    const float* lna_g = (const float*)d_in[10];
    const float* lna_b = (const float*)d_in[11];
    const float* mu_w1 = (const float*)d_in[12];
    const float* mu_b1 = (const float*)d_in[13];
    const float* mu_w2 = (const float*)d_in[14];
    const float* mu_b2 = (const float*)d_in[15];
    const float* ma_w1 = (const float*)d_in[16];
    const float* ma_b1 = (const float*)d_in[17];
    const float* ma_w2 = (const float*)d_in[18];
    const float* ma_b2 = (const float*)d_in[19];
    const float* rd_w1 = (const float*)d_in[20];
    const float* rd_b1 = (const float*)d_in[21];
    const float* rd_w2 = (const float*)d_in[22];
    const float* rd_b2 = (const float*)d_in[23];
    const float* rp_w1 = (const float*)d_in[24];
    const float* rp_b1 = (const float*)d_in[25];
    const float* rp_w2 = (const float*)d_in[26];
    const float* rp_b2 = (const float*)d_in[27];
    float* out = (float*)d_out;

    dim3 grid(BATCH / 256), block(256);
    hipLaunchKernelGGL(bgat_fwd, grid, block, 0, stream,
                       users, delta_init, power_init, Wu, Wa, We, av, Wres,
                       lnu_g, lnu_b, lna_g, lna_b,
                       mu_w1, mu_b1, mu_w2, mu_b2,
                       ma_w1, ma_b1, ma_w2, ma_b2,
                       rd_w1, rd_b1, rd_w2, rd_b2,
                       rp_w1, rp_b1, rp_w2, rp_b2, out);
}

// Round 2
// 381.301 us; speedup vs baseline: 3.3369x; 3.3369x over previous
//
#include <hip/hip_runtime.h>
#include <math.h>

// ---- Problem constants (fixed by the reference) ----
constexpr int BATCH = 262144;
constexpr int M_  = 2;
constexpr int N_  = 4;
constexpr int NB_ = 5;
constexpr int NH_ = 8;
constexpr int HD_ = 4;
constexpr int HID_ = 32;
constexpr float D_v    = 50.0f;
constexpr float HZ_v   = 5.0f;
constexpr float DMIN_v = 0.025f;
constexpr float PMAX_v = 1.0f;
constexpr float SCALE_v = 0.5f;                            // 1/sqrt(HD)
constexpr float BMAX_v  = 2.0f * D_v - (N_ - 1) * DMIN_v;  // 99.925

// ---- Packed-weight layout in d_ws / LDS (float offsets) ----
// HP   [5][8][40]  : per (layer,head): wu8 | wa8 | we4 | av4 | wres8 | lnu_g4 | lna_g4
// W1T  [5][2][32][16]: w1 transposed  (br 0=mu,1=ma; col i; out j)
// SGB  [5][2][2][16] : [d][br][0:G=sum g*w1 | 1:B=sum b*w1 + b1][j]
// W2P  [5][2][40]  : w2 row0(16) | row1(16) | b2(2) | pad(6)
// RO   [160]       : rd_w1(32) rd_b1(8) rd_w2(32) rd_b2(4) rp_w1(32) rp_b1(8) rp_w2(32) rp_b2(4) pad
constexpr int HP_OFF  = 0;      // 1600
constexpr int W1T_OFF = 1600;   // 5120
constexpr int SGB_OFF = 6720;   // 320
constexpr int W2_OFF  = 7040;   // 400
constexpr int RO_OFF  = 7440;   // 160
constexpr int TOTF    = 7600;   // floats (16B-divisible)

__device__ __forceinline__ float frcp(float x) { return __builtin_amdgcn_rcpf(x); }
#define LD4(p) (*(const float4*)(p))

__global__ __launch_bounds__(256) void pack_weights(
    const float* __restrict__ Wu, const float* __restrict__ Wa, const float* __restrict__ We,
    const float* __restrict__ av, const float* __restrict__ Wres,
    const float* __restrict__ lnu_g, const float* __restrict__ lnu_b,
    const float* __restrict__ lna_g, const float* __restrict__ lna_b,
    const float* __restrict__ mu_w1, const float* __restrict__ mu_b1,
    const float* __restrict__ mu_w2, const float* __restrict__ mu_b2,
    const float* __restrict__ ma_w1, const float* __restrict__ ma_b1,
    const float* __restrict__ ma_w2, const float* __restrict__ ma_b2,
    const float* __restrict__ rd_w1, const float* __restrict__ rd_b1,
    const float* __restrict__ rd_w2, const float* __restrict__ rd_b2,
    const float* __restrict__ rp_w1, const float* __restrict__ rp_b1,
    const float* __restrict__ rp_w2, const float* __restrict__ rp_b2,
    float* __restrict__ ws)
{
    const int t = threadIdx.x;
    // A: head packs
    for (int idx = t; idx < 1600; idx += 256) {
        const int d = idx / 320, r = idx % 320, k = r / 40, s = r % 40;
        const int dk = d * 8 + k;
        float v;
        if      (s <  8) v = Wu[dk * 8 + s];
        else if (s < 16) v = Wa[dk * 8 + (s - 8)];
        else if (s < 20) v = We[dk * 4 + (s - 16)];
        else if (s < 24) v = av[dk * 4 + (s - 20)];
        else if (s < 32) v = Wres[(d * 32 + k * 4) * 2 + (s - 24)];
        else if (s < 36) v = lnu_g[d * 32 + k * 4 + (s - 32)];
        else             v = lna_g[d * 32 + k * 4 + (s - 36)];
        ws[HP_OFF + idx] = v;
    }
    // B: transposed w1
    for (int idx = t; idx < 5120; idx += 256) {
        const int d = idx / 1024, r = idx % 1024, br = r / 512, r2 = r % 512;
        const int i = r2 / 16, j = r2 % 16;
        const float* w1 = br ? ma_w1 : mu_w1;
        ws[W1T_OFF + idx] = w1[(d * 16 + j) * 32 + i];
    }
    // C: LN-folded sums
    for (int idx = t; idx < 320; idx += 256) {
        const int d = idx / 64, r = idx % 64, br = r / 32, gb = (r % 32) / 16, j = r % 16;
        const float* w1 = (br ? ma_w1 : mu_w1) + (d * 16 + j) * 32;
        const float* gv = br ? lna_g : lnu_g;
        const float* bv = br ? lna_b : lnu_b;
        const float* b1 = br ? ma_b1 : mu_b1;
        float acc = 0.f;
        if (gb == 0) { for (int i = 0; i < 32; ++i) acc = fmaf(gv[d * 32 + i], w1[i], acc); }
        else { for (int i = 0; i < 32; ++i) acc = fmaf(bv[d * 32 + i], w1[i], acc); acc += b1[d * 16 + j]; }
        ws[SGB_OFF + idx] = acc;
    }
    // D: w2 + b2
    for (int idx = t; idx < 400; idx += 256) {
        const int d = idx / 80, r = idx % 80, br = r / 40, s = r % 40;
        const float* w2 = br ? ma_w2 : mu_w2;
        const float* b2 = br ? ma_b2 : mu_b2;
        float v = 0.f;
        if (s < 32) v = w2[d * 32 + s];
        else if (s < 34) v = b2[d * 2 + (s - 32)];
        ws[W2_OFF + idx] = v;
    }
    // E: readout
    for (int idx = t; idx < 160; idx += 256) {
        float v = 0.f;
        if      (idx <  32) v = rd_w1[idx];
        else if (idx <  40) v = rd_b1[idx - 32];
        else if (idx <  72) v = rd_w2[idx - 40];
        else if (idx <  76) v = rd_b2[idx - 72];
        else if (idx < 108) v = rp_w1[idx - 76];
        else if (idx < 116) v = rp_b1[idx - 108];
        else if (idx < 148) v = rp_w2[idx - 116];
        else if (idx < 152) v = rp_b2[idx - 148];
        ws[RO_OFF + idx] = v;
    }
}

// One thread = one batch element. Weights come from LDS (broadcast ds_read,
// conflict-free). Head loop rolled to keep the code in I$; per-head weights
// arrive as float4 LDS reads; each w1 column read feeds 32-64 FMAs.
__global__ __launch_bounds__(256) void bgat_fwd(
    const float* __restrict__ ws,
    const float* __restrict__ users, const float* __restrict__ delta_init,
    const float* __restrict__ power_init, float* __restrict__ out)
{
    __shared__ float smem[TOTF];
    {
        const float4* s4 = (const float4*)ws;
        float4* d4 = (float4*)smem;
        for (int i = threadIdx.x; i < TOTF / 4; i += 256) d4[i] = s4[i];
    }
    __syncthreads();

    const int b = blockIdx.x * 256 + threadIdx.x;

    float uf[M_][2];
    {
        const float4 u = ((const float4*)users)[b];
        uf[0][0] = u.x; uf[0][1] = u.y; uf[1][0] = u.z; uf[1][1] = u.w;
    }
    float af[N_][2];
    {
        const float4 p  = ((const float4*)power_init)[b];
        const float4 dl = ((const float4*)delta_init)[b];
        af[0][0] = p.x;  af[1][0] = p.y;  af[2][0] = p.z;  af[3][0] = p.w;
        af[0][1] = dl.x; af[1][1] = dl.y; af[2][1] = dl.z; af[3][1] = dl.w;
    }

#pragma unroll 1
    for (int d = 0; d < NB_; ++d) {
        const float* hpL  = smem + HP_OFF  + d * 320;
        const float* w1uL = smem + W1T_OFF + d * 1024;        // br=0, [i][j]
        const float* w1aL = w1uL + 512;                       // br=1
        const float* gbL  = smem + SGB_OFF + d * 64;
        const float* w2L  = smem + W2_OFF  + d * 80;

        // ---- node positions & edges ----
        float da[N_], sd = 1e-6f;
#pragma unroll
        for (int n = 0; n < N_; ++n) { da[n] = fmaxf(af[n][1], 0.f); sd += da[n]; }
        const float rs = BMAX_v * frcp(sd);
        float xpos[N_];
        {
            float cum = 0.f;
#pragma unroll
            for (int n = 0; n < N_; ++n) {
                cum = fmaf(rs, da[n], cum);
                xpos[n] = cum - D_v + DMIN_v * (float)n;
            }
        }
        float edge[M_][N_];
#pragma unroll
        for (int m = 0; m < M_; ++m)
#pragma unroll
            for (int n = 0; n < N_; ++n) {
                const float dx = uf[m][0] - xpos[n], dy = uf[m][1];
                edge[m][n] = sqrtf(fmaf(dx, dx, dy * dy));
            }

        // ---- deferred-LN accumulators ----
        float Smu[M_][16], Sma[N_][16];
        float sxu[M_], sxxu[M_], sxa[N_], sxxa[N_];
#pragma unroll
        for (int m = 0; m < M_; ++m) {
            sxu[m] = 0.f; sxxu[m] = 0.f;
#pragma unroll
            for (int j = 0; j < 16; ++j) Smu[m][j] = 0.f;
        }
#pragma unroll
        for (int n = 0; n < N_; ++n) {
            sxa[n] = 0.f; sxxa[n] = 0.f;
#pragma unroll
            for (int j = 0; j < 16; ++j) Sma[n][j] = 0.f;
        }

        // ---- attention heads (rolled: small code, LDS-broadcast weights) ----
#pragma unroll 1
        for (int k = 0; k < NH_; ++k) {
            const float* hp = hpL + k * 40;
            const float4 t0 = LD4(hp +  0), t1 = LD4(hp +  4);   // wu
            const float4 t2 = LD4(hp +  8), t3 = LD4(hp + 12);   // wa
            const float4 t4 = LD4(hp + 16);                      // we
            const float4 t5 = LD4(hp + 20);                      // av
            const float wuv[8] = {t0.x, t0.y, t0.z, t0.w, t1.x, t1.y, t1.z, t1.w};
            const float wav[8] = {t2.x, t2.y, t2.z, t2.w, t3.x, t3.y, t3.z, t3.w};
            const float wev[4] = {t4.x, t4.y, t4.z, t4.w};
            const float avv[4] = {t5.x, t5.y, t5.z, t5.w};

            float U[M_][HD_], A[N_][HD_];
#pragma unroll
            for (int h = 0; h < HD_; ++h) {
                const float w0 = wuv[2 * h], w1v = wuv[2 * h + 1];
#pragma unroll
                for (int m = 0; m < M_; ++m) U[m][h] = fmaf(uf[m][0], w0, uf[m][1] * w1v);
                const float a0 = wav[2 * h], a1 = wav[2 * h + 1];
#pragma unroll
                for (int n = 0; n < N_; ++n) A[n][h] = fmaf(af[n][0], a0, af[n][1] * a1);
            }

            float alpha[M_][N_];
#pragma unroll
            for (int m = 0; m < M_; ++m) {
                float sc[N_];
#pragma unroll
                for (int n = 0; n < N_; ++n) {
                    const float e = edge[m][n];
                    float s = 0.f;
#pragma unroll
                    for (int h = 0; h < HD_; ++h) {
                        float tt = U[m][h] + A[n][h] + e * wev[h];
                        tt = fmaxf(tt, 0.2f * tt);            // leaky_relu(0.2)
                        s = fmaf(tt, avv[h], s);
                    }
                    sc[n] = s * SCALE_v;
                }
                const float mx = fmaxf(fmaxf(sc[0], sc[1]), fmaxf(sc[2], sc[3]));
                float den = 0.f;
#pragma unroll
                for (int n = 0; n < N_; ++n) { sc[n] = __expf(sc[n] - mx); den += sc[n]; }
                const float rden = frcp(den);
#pragma unroll
                for (int n = 0; n < N_; ++n) alpha[m][n] = sc[n] * rden;
            }

            float eau[M_], ean[N_];
#pragma unroll
            for (int m = 0; m < M_; ++m) {
                float ea = 0.f;
#pragma unroll
                for (int n = 0; n < N_; ++n) ea = fmaf(edge[m][n], alpha[m][n], ea);
                eau[m] = ea;
            }
#pragma unroll
            for (int n = 0; n < N_; ++n)
                ean[n] = fmaf(edge[0][n], alpha[0][n], edge[1][n] * alpha[1][n]);

            const float4 t6 = LD4(hp + 24), t7 = LD4(hp + 28);   // Wres cols
            const float4 t8 = LD4(hp + 32);                      // lnu_g cols
            const float4 t9 = LD4(hp + 36);                      // lna_g cols
            const float wrv[8]  = {t6.x, t6.y, t6.z, t6.w, t7.x, t7.y, t7.z, t7.w};
            const float lugv[4] = {t8.x, t8.y, t8.z, t8.w};
            const float lagv[4] = {t9.x, t9.y, t9.z, t9.w};

#pragma unroll
            for (int h = 0; h < HD_; ++h) {
                const int col = k * HD_ + h;
                // --- user rows ---
                float yu[M_];
#pragma unroll
                for (int m = 0; m < M_; ++m) {
                    float uo = eau[m] * wev[h];
#pragma unroll
                    for (int n = 0; n < N_; ++n) uo = fmaf(A[n][h], alpha[m][n], uo);
                    const float x = uo + fmaf(uf[m][0], wrv[2 * h], uf[m][1] * wrv[2 * h + 1]);
                    sxu[m] += x;
                    sxxu[m] = fmaf(x, x, sxxu[m]);
                    yu[m] = x * lugv[h];
                }
                {
                    const float* wc = w1uL + col * 16;
#pragma unroll
                    for (int jj = 0; jj < 4; ++jj) {
                        const float4 w = LD4(wc + jj * 4);
#pragma unroll
                        for (int m = 0; m < M_; ++m) {
                            Smu[m][jj * 4 + 0] = fmaf(yu[m], w.x, Smu[m][jj * 4 + 0]);
                            Smu[m][jj * 4 + 1] = fmaf(yu[m], w.y, Smu[m][jj * 4 + 1]);
                            Smu[m][jj * 4 + 2] = fmaf(yu[m], w.z, Smu[m][jj * 4 + 2]);
                            Smu[m][jj * 4 + 3] = fmaf(yu[m], w.w, Smu[m][jj * 4 + 3]);
                        }
                    }
                }
                // --- node rows ---
                float ya[N_];
#pragma unroll
                for (int n = 0; n < N_; ++n) {
                    const float x = fmaf(U[0][h], alpha[0][n],
                                    fmaf(U[1][h], alpha[1][n], ean[n] * wev[h]));
                    sxa[n] += x;
                    sxxa[n] = fmaf(x, x, sxxa[n]);
                    ya[n] = x * lagv[h];
                }
                {
                    const float* wc = w1aL + col * 16;
#pragma unroll
                    for (int jj = 0; jj < 4; ++jj) {
                        const float4 w = LD4(wc + jj * 4);
#pragma unroll
                        for (int n = 0; n < N_; ++n) {
                            Sma[n][jj * 4 + 0] = fmaf(ya[n], w.x, Sma[n][jj * 4 + 0]);
                            Sma[n][jj * 4 + 1] = fmaf(ya[n], w.y, Sma[n][jj * 4 + 1]);
                            Sma[n][jj * 4 + 2] = fmaf(ya[n], w.z, Sma[n][jj * 4 + 2]);
                            Sma[n][jj * 4 + 3] = fmaf(ya[n], w.w, Sma[n][jj * 4 + 3]);
                        }
                    }
                }
            }
        } // heads

        // ---- user MLP (LN folded) ----
        float nuf[M_][2];
#pragma unroll
        for (int m = 0; m < M_; ++m) {
            const float mu_ = sxu[m] * (1.0f / HID_);
            const float var = sxxu[m] * (1.0f / HID_) - mu_ * mu_;
            const float inv = rsqrtf(var + 1e-5f);
            float o0 = w2L[32], o1 = w2L[33];
#pragma unroll
            for (int j = 0; j < 16; ++j) {
                const float pre = fmaf(inv, Smu[m][j] - mu_ * gbL[j], gbL[16 + j]);
                const float hh = fmaxf(pre, 0.f);
                o0 = fmaf(hh, w2L[j], o0);
                o1 = fmaf(hh, w2L[16 + j], o1);
            }
            nuf[m][0] = o0; nuf[m][1] = o1;
        }
        // ---- node MLP (LN folded) ----
        float naf[N_][2];
#pragma unroll
        for (int n = 0; n < N_; ++n) {
            const float mu_ = sxa[n] * (1.0f / HID_);
            const float var = sxxa[n] * (1.0f / HID_) - mu_ * mu_;
            const float inv = rsqrtf(var + 1e-5f);
            float o0 = w2L[72], o1 = w2L[73];
#pragma unroll
            for (int j = 0; j < 16; ++j) {
                const float pre = fmaf(inv, Sma[n][j] - mu_ * gbL[32 + j], gbL[48 + j]);
                const float hh = fmaxf(pre, 0.f);
                o0 = fmaf(hh, w2L[40 + j], o0);
                o1 = fmaf(hh, w2L[56 + j], o1);
            }
            naf[n][0] = o0; naf[n][1] = o1;
        }
#pragma unroll
        for (int m = 0; m < M_; ++m) { uf[m][0] = nuf[m][0]; uf[m][1] = nuf[m][1]; }
#pragma unroll
        for (int n = 0; n < N_; ++n) { af[n][0] = naf[n][0]; af[n][1] = naf[n][1]; }
    } // layers

    const float* ro = smem + RO_OFF;

    // ---- delta readout ----
    float hid[8];
#pragma unroll
    for (int j = 0; j < 8; ++j) {
        float s = ro[32 + j];
#pragma unroll
        for (int n = 0; n < N_; ++n) s = fmaf(af[n][1], ro[j * 4 + n], s);
        hid[j] = fmaxf(s, 0.f);
    }
    float daux[N_];
    float sumd = 0.f;
#pragma unroll
    for (int n = 0; n < N_; ++n) {
        float s = ro[72 + n];
#pragma unroll
        for (int j = 0; j < 8; ++j) s = fmaf(hid[j], ro[40 + n * 8 + j], s);
        daux[n] = fmaxf(s, 0.001f);
        sumd += daux[n];
    }
    const float sdl = BMAX_v * frcp(sumd);
    float sdelta[N_], xf[N_];
    {
        float cum = 0.f;
#pragma unroll
        for (int n = 0; n < N_; ++n) {
            sdelta[n] = sdl * daux[n];
            cum += sdelta[n];
            xf[n] = cum + DMIN_v * (float)n - D_v * (float)(n + 1);
        }
    }

    // ---- power readout ----
    float hp_[8];
#pragma unroll
    for (int j = 0; j < 8; ++j) {
        float s = ro[108 + j];
#pragma unroll
        for (int n = 0; n < N_; ++n) s = fmaf(af[n][0], ro[76 + j * 4 + n], s);
        hp_[j] = fmaxf(s, 0.f);
    }
    float paux[N_];
    float sump = 1e-6f;
#pragma unroll
    for (int n = 0; n < N_; ++n) {
        float s = ro[148 + n];
#pragma unroll
        for (int j = 0; j < 8; ++j) s = fmaf(hp_[j], ro[116 + n * 8 + j], s);
        paux[n] = fmaxf(s, 0.001f);
        sump += paux[n];
    }
    const float pscale = PMAX_v * frcp(fmaxf(PMAX_v, sump));

    // ---- stores: scaled_power (B,4) | scaled_delta (B,4) | final_positions (B,4,3)
    float4 sp;
    sp.x = pscale * paux[0]; sp.y = pscale * paux[1];
    sp.z = pscale * paux[2]; sp.w = pscale * paux[3];
    ((float4*)out)[b] = sp;

    float4 sdv;
    sdv.x = sdelta[0]; sdv.y = sdelta[1]; sdv.z = sdelta[2]; sdv.w = sdelta[3];
    ((float4*)(out + (size_t)4 * BATCH))[b] = sdv;

    float* pos = out + (size_t)8 * BATCH + (size_t)b * 12;
    float4 p0, p1, p2;
    p0.x = xf[0]; p0.y = 0.f;   p0.z = HZ_v;  p0.w = xf[1];
    p1.x = 0.f;   p1.y = HZ_v;  p1.z = xf[2]; p1.w = 0.f;
    p2.x = HZ_v;  p2.y = xf[3]; p2.z = 0.f;   p2.w = HZ_v;
    ((float4*)pos)[0] = p0;
    ((float4*)pos)[1] = p1;
    ((float4*)pos)[2] = p2;
}

extern "C" void kernel_launch(void* const* d_in, const int* in_sizes, int n_in,
                              void* d_out, int out_size, void* d_ws, size_t ws_size,
                              hipStream_t stream) {
    const float* users      = (const float*)d_in[0];
    const float* delta_init = (const float*)d_in[1];
    const float* power_init = (const float*)d_in[2];
    const float* Wu    = (const float*)d_in[3];
    const float* Wa    = (const float*)d_in[4];
    const float* We    = (const float*)d_in[5];
    const float* av    = (const float*)d_in[6];
    const float* Wres  = (const float*)d_in[7];
    const float* lnu_g = (const float*)d_in[8];
    const float* lnu_b = (const float*)d_in[9];
    const float* lna_g = (const float*)d_in[10];
    const float* lna_b = (const float*)d_in[11];
    const float* mu_w1 = (const float*)d_in[12];
    const float* mu_b1 = (const float*)d_in[13];
    const float* mu_w2 = (const float*)d_in[14];
    const float* mu_b2 = (const float*)d_in[15];
    const float* ma_w1 = (const float*)d_in[16];
    const float* ma_b1 = (const float*)d_in[17];
    const float* ma_w2 = (const float*)d_in[18];
    const float* ma_b2 = (const float*)d_in[19];
    const float* rd_w1 = (const float*)d_in[20];
    const float* rd_b1 = (const float*)d_in[21];
    const float* rd_w2 = (const float*)d_in[22];
    const float* rd_b2 = (const float*)d_in[23];
    const float* rp_w1 = (const float*)d_in[24];
    const float* rp_b1 = (const float*)d_in[25];
    const float* rp_w2 = (const float*)d_in[26];
    const float* rp_b2 = (const float*)d_in[27];
    float* ws  = (float*)d_ws;
    float* out = (float*)d_out;

    hipLaunchKernelGGL(pack_weights, dim3(1), dim3(256), 0, stream,
                       Wu, Wa, We, av, Wres, lnu_g, lnu_b, lna_g, lna_b,
                       mu_w1, mu_b1, mu_w2, mu_b2, ma_w1, ma_b1, ma_w2, ma_b2,
                       rd_w1, rd_b1, rd_w2, rd_b2, rp_w1, rp_b1, rp_w2, rp_b2, ws);

    hipLaunchKernelGGL(bgat_fwd, dim3(BATCH / 256), dim3(256), 0, stream,
                       ws, users, delta_init, power_init, out);
}